// Round 2
// baseline (9205.047 us; speedup 1.0000x reference)
//
#include <hip/hip_runtime.h>
#include <hip/hip_bf16.h>
#include <cstdint>
#include <cstddef>

#define HH 64
#define BB 256
#define TT 200
#define DL 711
#define DA 300
#define DV 74
#define DD 1085
#define GXW 768   // 3 * 4H

// ---------------------------------------------------------------------------
// Phase 1: input projections for all (t,b):
//   gx[(t*256+b)*768 + mod*256 + n] = sum_d x[b][t][off_mod + d] * wih_mod[d][n]
// Tiled fp32 GEMM: BM=64 rows, BN=256 cols (full), BK=32. 256 threads,
// 8x8 register tile per thread.
// ---------------------------------------------------------------------------
__global__ __launch_bounds__(256) void proj_kernel(
    const float* __restrict__ x,
    const float* __restrict__ wl,
    const float* __restrict__ wa,
    const float* __restrict__ wv,
    float* __restrict__ gx)
{
    const int mod = blockIdx.y;
    const int K   = (mod == 0) ? DL : (mod == 1 ? DA : DV);
    const int off = (mod == 0) ? 0  : (mod == 1 ? DL : (DL + DA));
    const float* __restrict__ W = (mod == 0) ? wl : (mod == 1 ? wa : wv);

    const int tid = threadIdx.x;
    const int r0  = blockIdx.x * 64;

    __shared__ float As[32][65];    // [k][m], +1 pad kills write conflicts
    __shared__ float Bs[32][256];   // [k][n]

    const int tm = (tid >> 5) << 3;   // 0..56
    const int tn = (tid & 31) << 3;   // 0..248

    // A-load mapping: thread covers row am, 8 consecutive k's
    const int am = tid >> 2;
    const int ad = (tid & 3) << 3;
    const int r  = r0 + am;
    const int b  = r & 255;
    const int t  = r >> 8;
    const float* __restrict__ xrow = x + ((size_t)b * TT + t) * DD + off;

    // B-load mapping: thread covers k-row bk, 8 float4's
    const int bk = tid >> 3;
    const int bf = tid & 7;

    float acc[8][8];
    #pragma unroll
    for (int i = 0; i < 8; ++i)
        #pragma unroll
        for (int j = 0; j < 8; ++j) acc[i][j] = 0.f;

    for (int k0 = 0; k0 < K; k0 += 32) {
        // load A tile (zero-pad K remainder)
        #pragma unroll
        for (int u = 0; u < 8; ++u) {
            int d = k0 + ad + u;
            As[ad + u][am] = (d < K) ? xrow[d] : 0.f;
        }
        // load B tile
        {
            const bool kin = (k0 + bk) < K;
            const float4* __restrict__ wrow4 =
                (const float4*)(W + (size_t)(k0 + bk) * 256);
            #pragma unroll
            for (int u = 0; u < 8; ++u) {
                int c4 = bf + u * 8;   // 0..63
                float4 v = kin ? wrow4[c4] : make_float4(0.f, 0.f, 0.f, 0.f);
                *(float4*)&Bs[bk][c4 << 2] = v;
            }
        }
        __syncthreads();

        #pragma unroll
        for (int kk = 0; kk < 32; ++kk) {
            float a[8], bb[8];
            #pragma unroll
            for (int i = 0; i < 8; ++i) a[i] = As[kk][tm + i];
            float4 b0 = *(const float4*)&Bs[kk][tn];
            float4 b1 = *(const float4*)&Bs[kk][tn + 4];
            bb[0] = b0.x; bb[1] = b0.y; bb[2] = b0.z; bb[3] = b0.w;
            bb[4] = b1.x; bb[5] = b1.y; bb[6] = b1.z; bb[7] = b1.w;
            #pragma unroll
            for (int i = 0; i < 8; ++i)
                #pragma unroll
                for (int j = 0; j < 8; ++j)
                    acc[i][j] += a[i] * bb[j];
        }
        __syncthreads();
    }

    // store 8 rows x 8 cols per thread
    #pragma unroll
    for (int i = 0; i < 8; ++i) {
        size_t row = (size_t)(r0 + tm + i);
        float* o = gx + row * GXW + mod * 256 + tn;
        *(float4*)&o[0] = make_float4(acc[i][0], acc[i][1], acc[i][2], acc[i][3]);
        *(float4*)&o[4] = make_float4(acc[i][4], acc[i][5], acc[i][6], acc[i][7]);
    }
}

// ---------------------------------------------------------------------------
// Phase 2: the 200-step recurrence. One block per 4 batch rows (64 blocks,
// 512 threads). All state in LDS; weights streamed from L2, reused across
// the 4 rows in registers. Final out-projection fused at the end.
// c_star double-buffer: logical index L in [0,384): phys = (L + oldb) mod 384.
// 10 barriers per step (was 17): split-K stages use pair-shuffle reduction,
// gamma1/gamma2 MLPs are merged, chat/gamma1 fused into the mem-update phase.
// ---------------------------------------------------------------------------
__global__ __launch_bounds__(512) void recur_kernel(
    const float* __restrict__ gx,
    const float* __restrict__ whhl,
    const float* __restrict__ whha,
    const float* __restrict__ whhv,
    const float* __restrict__ a1w1, const float* __restrict__ a1b1,
    const float* __restrict__ a1w2, const float* __restrict__ a1b2,
    const float* __restrict__ a2w1, const float* __restrict__ a2b1,
    const float* __restrict__ a2w2, const float* __restrict__ a2b2,
    const float* __restrict__ g1w1, const float* __restrict__ g1b1,
    const float* __restrict__ g1w2, const float* __restrict__ g1b2,
    const float* __restrict__ g2w1, const float* __restrict__ g2b1,
    const float* __restrict__ g2w2, const float* __restrict__ g2b2,
    const float* __restrict__ ow1,  const float* __restrict__ ow2,
    float* __restrict__ out)
{
    const int tid = threadIdx.x;
    const int r0  = blockIdx.x * 4;

    __shared__ float cstar[4][384];   // [r][phys]; halves alternate old/new c
    __shared__ float hbuf[4][192];    // h_l|h_a|h_v
    __shared__ float memb[4][64];
    __shared__ float att[4][384];     // attended (logical order)
    __shared__ float sbuf[4][384];    // pre-softmax scores / exp values
    __shared__ float actb[4][64];     // relu hidden (att1 then att2)
    __shared__ float hid2[2][4][64];  // g1/g2 layer-1 hidden
    __shared__ float gates[4][768];
    __shared__ float wr1[4][2];
    __shared__ float wr2[4][2];

    for (int i = tid; i < 4 * 384; i += 512) ((float*)cstar)[i] = 0.f;
    for (int i = tid; i < 4 * 192; i += 512) ((float*)hbuf)[i]  = 0.f;
    for (int i = tid; i < 4 * 64;  i += 512) ((float*)memb)[i]  = 0.f;
    __syncthreads();

    for (int t = 0; t < TT; ++t) {
        const int oldb = (t & 1) * 192;
        const int newb = oldb ^ 192;

        // ---- P1: gates[r][k] = gx + h @ whh.  1536 (k, i-half) units,
        //          3 per thread, pair-shuffle combine. ----
        {
            const float* __restrict__ gxt = gx + ((size_t)t * 256 + r0) * GXW;
            const int seg = tid & 1;           // which i-half
            float acc[3][4];
            int kq[3];
            #pragma unroll
            for (int q = 0; q < 3; ++q) {
                const int u = tid + (q << 9);  // tid, tid+512, tid+1024
                const int k = u >> 1;
                kq[q] = k;
                const int m  = k >> 8;
                const int kk = k & 255;
                const float* __restrict__ Wp =
                    (m == 0 ? whhl : (m == 1 ? whha : whhv)) + kk + seg * 32 * 256;
                const int hb = m * 64 + seg * 32;
                float a0 = 0.f, a1 = 0.f, a2 = 0.f, a3 = 0.f;
                #pragma unroll 8
                for (int i = 0; i < 32; ++i) {
                    float w = Wp[i * 256];
                    a0 += hbuf[0][hb + i] * w;
                    a1 += hbuf[1][hb + i] * w;
                    a2 += hbuf[2][hb + i] * w;
                    a3 += hbuf[3][hb + i] * w;
                }
                acc[q][0] = a0; acc[q][1] = a1; acc[q][2] = a2; acc[q][3] = a3;
            }
            #pragma unroll
            for (int q = 0; q < 3; ++q) {
                #pragma unroll
                for (int rr = 0; rr < 4; ++rr)
                    acc[q][rr] += __shfl_xor(acc[q][rr], 1);
                if (seg == 0) {
                    const int k = kq[q];
                    gates[0][k] = acc[q][0] + gxt[0 * GXW + k];
                    gates[1][k] = acc[q][1] + gxt[1 * GXW + k];
                    gates[2][k] = acc[q][2] + gxt[2 * GXW + k];
                    gates[3][k] = acc[q][3] + gxt[3 * GXW + k];
                }
            }
        }
        __syncthreads();

        // ---- P2: cell update; write new c into cstar[newb], h ----
        for (int idx = tid; idx < 4 * 192; idx += 512) {
            const int rr = idx / 192;
            const int mj = idx - rr * 192;
            const int m  = mj >> 6;
            const int j  = mj & 63;
            const int gb = m * 256 + j;
            float ig = gates[rr][gb];
            float fg = gates[rr][gb + 64];
            float gg = gates[rr][gb + 128];
            float og = gates[rr][gb + 192];
            float iv = 1.f / (1.f + expf(-ig));
            float fv = 1.f / (1.f + expf(-fg));
            float ov = 1.f / (1.f + expf(-og));
            float gv = tanhf(gg);
            float co = cstar[rr][oldb + mj];
            float cn = fv * co + iv * gv;
            cstar[rr][newb + mj] = cn;
            hbuf[rr][mj] = ov * tanhf(cn);
        }
        __syncthreads();

        // ---- P3: att1 layer1 (384 -> 64), pair-shuffle split-K ----
        {
            const int o   = tid >> 1;          // 0..255
            const int seg = tid & 1;
            const int rr  = o >> 6, j = o & 63;
            const int ib  = seg * 192;
            float s = 0.f;
            #pragma unroll 8
            for (int ii = 0; ii < 192; ++ii) {
                int i = ib + ii;
                int ip = i + oldb; if (ip >= 384) ip -= 384;
                s += cstar[rr][ip] * a1w1[i * 64 + j];
            }
            s += __shfl_xor(s, 1);
            if (seg == 0) actb[rr][j] = fmaxf(s + a1b1[j], 0.f);
        }
        __syncthreads();

        // ---- P4: att1 layer2 (64 -> 384) + bias -> sbuf ----
        if (tid < 384) {
            const int L = tid;
            float bv = a1b2[L];
            float a0 = bv, a1 = bv, a2 = bv, a3 = bv;
            #pragma unroll 8
            for (int i = 0; i < 64; ++i) {
                float w = a1w2[i * 384 + L];
                a0 += actb[0][i] * w;
                a1 += actb[1][i] * w;
                a2 += actb[2][i] * w;
                a3 += actb[3][i] * w;
            }
            sbuf[0][L] = a0; sbuf[1][L] = a1; sbuf[2][L] = a2; sbuf[3][L] = a3;
        }
        __syncthreads();

        // ---- P5: softmax max ----
        {
            const int rr = tid >> 7, c = tid & 127;
            float mx = fmaxf(sbuf[rr][c], fmaxf(sbuf[rr][c + 128], sbuf[rr][c + 256]));
            #pragma unroll
            for (int o = 32; o > 0; o >>= 1) mx = fmaxf(mx, __shfl_xor(mx, o));
            if ((tid & 63) == 0) wr1[rr][(tid >> 6) & 1] = mx;
        }
        __syncthreads();

        // ---- P6: softmax exp + sum ----
        {
            const int rr = tid >> 7, c = tid & 127;
            float mx = fmaxf(wr1[rr][0], wr1[rr][1]);
            float e0 = expf(sbuf[rr][c]       - mx);
            float e1 = expf(sbuf[rr][c + 128] - mx);
            float e2 = expf(sbuf[rr][c + 256] - mx);
            sbuf[rr][c] = e0; sbuf[rr][c + 128] = e1; sbuf[rr][c + 256] = e2;
            float sm = e0 + e1 + e2;
            #pragma unroll
            for (int o = 32; o > 0; o >>= 1) sm += __shfl_xor(sm, o);
            if ((tid & 63) == 0) wr2[rr][(tid >> 6) & 1] = sm;
        }
        __syncthreads();

        // ---- P7: attended = p * c_star ----
        {
            const int rr = tid >> 7, c = tid & 127;
            float inv = 1.f / (wr2[rr][0] + wr2[rr][1]);
            #pragma unroll
            for (int q = 0; q < 3; ++q) {
                int L = c + q * 128;
                int ip = L + oldb; if (ip >= 384) ip -= 384;
                att[rr][L] = sbuf[rr][L] * inv * cstar[rr][ip];
            }
        }
        __syncthreads();

        // ---- P8: att2 layer1 (384 -> 64), pair-shuffle split-K ----
        {
            const int o   = tid >> 1;
            const int seg = tid & 1;
            const int rr  = o >> 6, j = o & 63;
            const int ib  = seg * 192;
            float s = 0.f;
            #pragma unroll 8
            for (int ii = 0; ii < 192; ++ii) {
                int i = ib + ii;
                s += att[rr][i] * a2w1[i * 64 + j];
            }
            s += __shfl_xor(s, 1);
            if (seg == 0) actb[rr][j] = fmaxf(s + a2b1[j], 0.f);
        }
        __syncthreads();

        // ---- P9: g1 AND g2 layer1 (448 -> 64 each), 512 outputs ----
        {
            const int which = tid >> 8;        // 0: g1, 1: g2
            const int o  = tid & 255;
            const int rr = o >> 6, j = o & 63;
            const float* __restrict__ W  = which ? g2w1 : g1w1;
            const float* __restrict__ Bv = which ? g2b1 : g1b1;
            float s = Bv[j];
            #pragma unroll 8
            for (int i = 0; i < 384; ++i) s += att[rr][i] * W[i * 64 + j];
            #pragma unroll
            for (int i = 0; i < 64; ++i) s += memb[rr][i] * W[(384 + i) * 64 + j];
            hid2[which][rr][j] = fmaxf(s, 0.f);
        }
        __syncthreads();

        // ---- P10: chat + gamma1 + gamma2 + mem update, fused ----
        if (tid < 256) {
            const int rr = tid >> 6, j = tid & 63;
            float sc = a2b2[j], s1 = g1b2[j], s2 = g2b2[j];
            #pragma unroll 8
            for (int i = 0; i < 64; ++i) {
                sc += actb[rr][i]    * a2w2[i * 64 + j];
                s1 += hid2[0][rr][i] * g1w2[i * 64 + j];
                s2 += hid2[1][rr][i] * g2w2[i * 64 + j];
            }
            float chat_v = tanhf(sc);
            float g1v = 1.f / (1.f + expf(-s1));
            float g2v = 1.f / (1.f + expf(-s2));
            memb[rr][j] = g1v * memb[rr][j] + g2v * chat_v;
        }
        __syncthreads();
    }

    // ---- fused final projection: out = relu(last_hs @ ow1) @ ow2 ----
    if (tid < 256) {
        const int rr = tid >> 6, j = tid & 63;
        float acc = 0.f;
        #pragma unroll 4
        for (int i = 0; i < 256; ++i) {
            float xv = (i < 192) ? hbuf[rr][i] : memb[rr][i - 192];
            acc += xv * ow1[i * 64 + j];
        }
        float y = fmaxf(acc, 0.f) * ow2[j];
        #pragma unroll
        for (int o = 32; o > 0; o >>= 1) y += __shfl_xor(y, o);
        if (j == 0) out[r0 + rr] = y;
    }
}

// ---------------------------------------------------------------------------
extern "C" void kernel_launch(void* const* d_in, const int* in_sizes, int n_in,
                              void* d_out, int out_size, void* d_ws, size_t ws_size,
                              hipStream_t stream)
{
    const float* x    = (const float*)d_in[0];
    const float* wihl = (const float*)d_in[1];
    const float* whhl = (const float*)d_in[2];
    const float* wiha = (const float*)d_in[3];
    const float* whha = (const float*)d_in[4];
    const float* wihv = (const float*)d_in[5];
    const float* whhv = (const float*)d_in[6];
    const float* a1w1 = (const float*)d_in[7];
    const float* a1b1 = (const float*)d_in[8];
    const float* a1w2 = (const float*)d_in[9];
    const float* a1b2 = (const float*)d_in[10];
    const float* a2w1 = (const float*)d_in[11];
    const float* a2b1 = (const float*)d_in[12];
    const float* a2w2 = (const float*)d_in[13];
    const float* a2b2 = (const float*)d_in[14];
    const float* g1w1 = (const float*)d_in[15];
    const float* g1b1 = (const float*)d_in[16];
    const float* g1w2 = (const float*)d_in[17];
    const float* g1b2 = (const float*)d_in[18];
    const float* g2w1 = (const float*)d_in[19];
    const float* g2b1 = (const float*)d_in[20];
    const float* g2w2 = (const float*)d_in[21];
    const float* g2b2 = (const float*)d_in[22];
    const float* ow1  = (const float*)d_in[23];
    const float* ow2  = (const float*)d_in[24];

    float* gx  = (float*)d_ws;            // 51200 * 768 floats = 157.3 MB
    float* out = (float*)d_out;

    dim3 grid1(800, 3, 1);
    proj_kernel<<<grid1, dim3(256, 1, 1), 0, stream>>>(x, wihl, wiha, wihv, gx);

    recur_kernel<<<dim3(64, 1, 1), dim3(512, 1, 1), 0, stream>>>(
        gx, whhl, whha, whhv,
        a1w1, a1b1, a1w2, a1b2,
        a2w1, a2b1, a2w2, a2b2,
        g1w1, g1b1, g1w2, g1b2,
        g2w1, g2b1, g2w2, g2b2,
        ow1, ow2, out);
}

// Round 4
// 2821.826 us; speedup vs baseline: 3.2621x; 3.2621x over previous
//
#include <hip/hip_runtime.h>
#include <hip/hip_bf16.h>
#include <cstdint>
#include <cstddef>

#define HH 64
#define BB 256
#define TT 200
#define DL 711
#define DA 300
#define DV 74
#define DD 1085
#define GXW 768                    // 3 * 4H
#define NROW (TT * BB)             // 51200
#define HPOFF ((size_t)NROW * GXW) // float offset of h-partials in ws

// gx row (t,b) column layout through the phases:
//  Phase A writes gates_x: L gates 0..256, A gates 256..512, V gates 512..768
//  Phase B (step t) consumes gates of row t, then stashes (per modality m):
//    c_t    -> m*256 + 0  .. +64
//    c_{t+1}-> m*256 + 64 .. +128
//  Phase C writes: chat -> 192..256, PRE1 -> 384..448, PRE2 -> 448..512
//  Phase D reads chat/PRE1/PRE2 + hp; writes out.

// ---------------------------------------------------------------------------
// Phase A: input projections gx = x @ wih for all (t,b). Unchanged (verified).
// ---------------------------------------------------------------------------
__global__ __launch_bounds__(256) void proj_kernel(
    const float* __restrict__ x,
    const float* __restrict__ wl,
    const float* __restrict__ wa,
    const float* __restrict__ wv,
    float* __restrict__ gx)
{
    const int mod = blockIdx.y;
    const int K   = (mod == 0) ? DL : (mod == 1 ? DA : DV);
    const int off = (mod == 0) ? 0  : (mod == 1 ? DL : (DL + DA));
    const float* __restrict__ W = (mod == 0) ? wl : (mod == 1 ? wa : wv);

    const int tid = threadIdx.x;
    const int r0  = blockIdx.x * 64;

    __shared__ float As[32][65];
    __shared__ float Bs[32][256];

    const int tm = (tid >> 5) << 3;
    const int tn = (tid & 31) << 3;

    const int am = tid >> 2;
    const int ad = (tid & 3) << 3;
    const int r  = r0 + am;
    const int b  = r & 255;
    const int t  = r >> 8;
    const float* __restrict__ xrow = x + ((size_t)b * TT + t) * DD + off;

    const int bk = tid >> 3;
    const int bf = tid & 7;

    float acc[8][8];
    #pragma unroll
    for (int i = 0; i < 8; ++i)
        #pragma unroll
        for (int j = 0; j < 8; ++j) acc[i][j] = 0.f;

    for (int k0 = 0; k0 < K; k0 += 32) {
        #pragma unroll
        for (int u = 0; u < 8; ++u) {
            int d = k0 + ad + u;
            As[ad + u][am] = (d < K) ? xrow[d] : 0.f;
        }
        {
            const bool kin = (k0 + bk) < K;
            const float4* __restrict__ wrow4 =
                (const float4*)(W + (size_t)(k0 + bk) * 256);
            #pragma unroll
            for (int u = 0; u < 8; ++u) {
                int c4 = bf + u * 8;
                float4 v = kin ? wrow4[c4] : make_float4(0.f, 0.f, 0.f, 0.f);
                *(float4*)&Bs[bk][c4 << 2] = v;
            }
        }
        __syncthreads();

        #pragma unroll
        for (int kk = 0; kk < 32; ++kk) {
            float a[8], bb[8];
            #pragma unroll
            for (int i = 0; i < 8; ++i) a[i] = As[kk][tm + i];
            float4 b0 = *(const float4*)&Bs[kk][tn];
            float4 b1 = *(const float4*)&Bs[kk][tn + 4];
            bb[0] = b0.x; bb[1] = b0.y; bb[2] = b0.z; bb[3] = b0.w;
            bb[4] = b1.x; bb[5] = b1.y; bb[6] = b1.z; bb[7] = b1.w;
            #pragma unroll
            for (int i = 0; i < 8; ++i)
                #pragma unroll
                for (int j = 0; j < 8; ++j)
                    acc[i][j] += a[i] * bb[j];
        }
        __syncthreads();
    }

    #pragma unroll
    for (int i = 0; i < 8; ++i) {
        size_t row = (size_t)(r0 + tm + i);
        float* o = gx + row * GXW + mod * 256 + tn;
        *(float4*)&o[0] = make_float4(acc[i][0], acc[i][1], acc[i][2], acc[i][3]);
        *(float4*)&o[4] = make_float4(acc[i][4], acc[i][5], acc[i][6], acc[i][7]);
    }
}

// ---------------------------------------------------------------------------
// Phase B: 3 independent LSTM chains. Grid (3 modalities, 32 row-groups),
// 256 threads, R=8 rows/block. Stashes c_star into gx; h-partial into hp.
// ---------------------------------------------------------------------------
__global__ __launch_bounds__(256) void lstm_kernel(
    float* gx,                          // read gates + write stash (same buf)
    const float* __restrict__ whhl,
    const float* __restrict__ whha,
    const float* __restrict__ whhv,
    const float* __restrict__ ow1,
    float* __restrict__ hp)
{
    const int m   = blockIdx.x;
    const int b0  = blockIdx.y * 8;
    const int tid = threadIdx.x;
    const float* __restrict__ W = (m == 0) ? whhl : ((m == 1) ? whha : whhv);

    __shared__ float h[8][64];
    __shared__ float c[8][64];
    __shared__ float gb[8][256];

    for (int i = tid; i < 512; i += 256) { ((float*)h)[i] = 0.f; ((float*)c)[i] = 0.f; }
    __syncthreads();

    for (int t = 0; t < TT; ++t) {
        // gate phase: thread k computes gate col k for 8 rows
        {
            const int k = tid;
            const float* gxt = gx + ((size_t)(t * BB + b0)) * GXW + m * 256 + k;
            float s[8];
            #pragma unroll
            for (int r = 0; r < 8; ++r) s[r] = gxt[(size_t)r * GXW];
            #pragma unroll 16
            for (int i = 0; i < 64; ++i) {
                float w = W[i * 256 + k];
                #pragma unroll
                for (int r = 0; r < 8; ++r) s[r] += h[r][i] * w;
            }
            #pragma unroll
            for (int r = 0; r < 8; ++r) gb[r][k] = s[r];
        }
        __syncthreads();
        // update phase: thread (rr=tid>>6, j) handles rows rr and rr+4
        {
            const int j = tid & 63, rr = tid >> 6;
            #pragma unroll
            for (int u = 0; u < 2; ++u) {
                const int r = rr + u * 4;
                float ig = gb[r][j];
                float fg = gb[r][j + 64];
                float gg = gb[r][j + 128];
                float og = gb[r][j + 192];
                float iv = 1.f / (1.f + expf(-ig));
                float fv = 1.f / (1.f + expf(-fg));
                float ov = 1.f / (1.f + expf(-og));
                float gv = tanhf(gg);
                float co = c[r][j];
                float cn = fv * co + iv * gv;
                float* grow = gx + ((size_t)(t * BB + b0 + r)) * GXW + m * 256;
                grow[j]      = co;   // c_t
                grow[64 + j] = cn;   // c_{t+1}
                c[r][j] = cn;
                h[r][j] = ov * tanhf(cn);
            }
        }
        __syncthreads();
    }

    // h-partial: hp[(m*256+b)*64+j] = sum_i h[b][i] * ow1[(m*64+i)*64+j]
    {
        const int j = tid & 63, rr = tid >> 6;
        #pragma unroll
        for (int u = 0; u < 2; ++u) {
            const int r = rr + u * 4;
            float s = 0.f;
            for (int i = 0; i < 64; ++i)
                s += h[r][i] * ow1[(m * 64 + i) * 64 + j];
            hp[((size_t)m * BB + b0 + r) * 64 + j] = s;
        }
    }
}

// ---------------------------------------------------------------------------
// Phase C: batched attention path for all 51200 rows. 32 rows/block,
// 256 threads. Computes A1, softmax, attended, then chat/PRE1/PRE2.
// ---------------------------------------------------------------------------
__global__ __launch_bounds__(256) void att_kernel(
    float* gx,
    const float* __restrict__ a1w1, const float* __restrict__ a1b1,
    const float* __restrict__ a1w2, const float* __restrict__ a1b2,
    const float* __restrict__ a2w1, const float* __restrict__ a2b1,
    const float* __restrict__ a2w2, const float* __restrict__ a2b2,
    const float* __restrict__ g1w1, const float* __restrict__ g1b1,
    const float* __restrict__ g2w1, const float* __restrict__ g2b1)
{
    const int tid = threadIdx.x;
    const size_t R0 = (size_t)blockIdx.x * 32;

    __shared__ float cs[32][384];   // c_star, later attended (in-place)
    __shared__ float hb[32][64];    // A1, later A2

    // load c_star (scattered col map -> logical order [c_l c_a c_v nc_l nc_a nc_v])
    for (int u = 0; u < 48; ++u) {
        int flat = tid + u * 256;           // 0..12287
        int rr = flat / 384;
        int i  = flat - rr * 384;
        int col;
        if (i < 192) col = (i >> 6) * 256 + (i & 63);
        else { int jj = i - 192; col = (jj >> 6) * 256 + 64 + (jj & 63); }
        cs[rr][i] = gx[(R0 + rr) * GXW + col];
    }
    __syncthreads();

    const int j   = tid & 63;
    const int rrg = tid >> 6;              // row group: rows rrg*8 .. +7

    // A1 = relu(cs @ a1w1 + b1)
    {
        float acc[8];
        #pragma unroll
        for (int u = 0; u < 8; ++u) acc[u] = a1b1[j];
        for (int i = 0; i < 384; ++i) {
            float w = a1w1[i * 64 + j];
            #pragma unroll
            for (int u = 0; u < 8; ++u) acc[u] += cs[rrg * 8 + u][i] * w;
        }
        #pragma unroll
        for (int u = 0; u < 8; ++u) hb[rrg * 8 + u][j] = fmaxf(acc[u], 0.f);
    }
    __syncthreads();

    // scores + softmax + attended (per wave: 8 rows, weight loads amortized)
    {
        const int lane = tid & 63;
        float sc[6][8];
        #pragma unroll
        for (int q = 0; q < 6; ++q) {
            float bv = a1b2[lane + q * 64];
            #pragma unroll
            for (int u = 0; u < 8; ++u) sc[q][u] = bv;
        }
        for (int i = 0; i < 64; ++i) {
            float av[8];
            #pragma unroll
            for (int u = 0; u < 8; ++u) av[u] = hb[rrg * 8 + u][i];
            #pragma unroll
            for (int q = 0; q < 6; ++q) {
                float w = a1w2[i * 384 + lane + q * 64];
                #pragma unroll
                for (int u = 0; u < 8; ++u) sc[q][u] += av[u] * w;
            }
        }
        #pragma unroll
        for (int u = 0; u < 8; ++u) {
            const int r = rrg * 8 + u;
            float mx = sc[0][u];
            #pragma unroll
            for (int q = 1; q < 6; ++q) mx = fmaxf(mx, sc[q][u]);
            #pragma unroll
            for (int o = 32; o > 0; o >>= 1) mx = fmaxf(mx, __shfl_xor(mx, o));
            float sm = 0.f;
            float e[6];
            #pragma unroll
            for (int q = 0; q < 6; ++q) { e[q] = expf(sc[q][u] - mx); sm += e[q]; }
            #pragma unroll
            for (int o = 32; o > 0; o >>= 1) sm += __shfl_xor(sm, o);
            float inv = 1.f / sm;
            #pragma unroll
            for (int q = 0; q < 6; ++q) {
                int L = lane + q * 64;
                cs[r][L] = e[q] * inv * cs[r][L];
            }
        }
    }
    __syncthreads();

    // A2 / PRE1 / PRE2 (attended @ {a2w1, g1w1[0:384], g2w1[0:384]} + biases)
    {
        float sa[8], s1[8], s2[8];
        #pragma unroll
        for (int u = 0; u < 8; ++u) { sa[u] = a2b1[j]; s1[u] = g1b1[j]; s2[u] = g2b1[j]; }
        for (int i = 0; i < 384; ++i) {
            float wa = a2w1[i * 64 + j];
            float w1 = g1w1[i * 64 + j];
            float w2 = g2w1[i * 64 + j];
            #pragma unroll
            for (int u = 0; u < 8; ++u) {
                float v = cs[rrg * 8 + u][i];
                sa[u] += v * wa; s1[u] += v * w1; s2[u] += v * w2;
            }
        }
        #pragma unroll
        for (int u = 0; u < 8; ++u) {
            const size_t r = R0 + rrg * 8 + u;
            float* grow = gx + r * GXW;
            grow[384 + j] = s1[u];      // PRE1
            grow[448 + j] = s2[u];      // PRE2
            hb[rrg * 8 + u][j] = fmaxf(sa[u], 0.f);   // A2 (overwrite A1)
        }
    }
    __syncthreads();

    // chat = tanh(A2 @ a2w2 + b2)
    {
        float acc[8];
        #pragma unroll
        for (int u = 0; u < 8; ++u) acc[u] = a2b2[j];
        for (int i = 0; i < 64; ++i) {
            float w = a2w2[i * 64 + j];
            #pragma unroll
            for (int u = 0; u < 8; ++u) acc[u] += hb[rrg * 8 + u][i] * w;
        }
        #pragma unroll
        for (int u = 0; u < 8; ++u)
            gx[(R0 + rrg * 8 + u) * GXW + 192 + j] = tanhf(acc[u]);
    }
}

// ---------------------------------------------------------------------------
// Phase D: sequential mem recurrence. 256 blocks x 64 threads (1 wave, no
// barriers in the loop). All 4 weight mats in LDS (64 KB), loaded once.
// ---------------------------------------------------------------------------
__global__ __launch_bounds__(64) void mem_kernel(
    const float* __restrict__ gx,
    const float* __restrict__ g1w1, const float* __restrict__ g1w2, const float* __restrict__ g1b2,
    const float* __restrict__ g2w1, const float* __restrict__ g2w2, const float* __restrict__ g2b2,
    const float* __restrict__ ow1,  const float* __restrict__ ow2,
    const float* __restrict__ hp,
    float* __restrict__ out)
{
    const int j = threadIdx.x;
    const int b = blockIdx.x;

    __shared__ float Wm1[64][64];
    __shared__ float Wm2[64][64];
    __shared__ float Wf1[64][64];
    __shared__ float Wf2[64][64];

    for (int i = 0; i < 64; ++i) {
        Wm1[i][j] = g1w1[(384 + i) * 64 + j];
        Wm2[i][j] = g2w1[(384 + i) * 64 + j];
        Wf1[i][j] = g1w2[i * 64 + j];
        Wf2[i][j] = g2w2[i * 64 + j];
    }
    const float bf1 = g1b2[j], bf2 = g2b2[j];
    __syncthreads();

    float mem = 0.f;
    const float* base0 = gx + (size_t)b * GXW;
    float cj = base0[192 + j];
    float p1 = base0[384 + j];
    float p2 = base0[448 + j];

    for (int t = 0; t < TT; ++t) {
        float ncj = 0.f, np1 = 0.f, np2 = 0.f;
        if (t + 1 < TT) {
            const float* nb = gx + ((size_t)(t + 1) * BB + b) * GXW;
            ncj = nb[192 + j]; np1 = nb[384 + j]; np2 = nb[448 + j];
        }
        // hid = relu(PRE + mem @ Wm)
        float s1 = p1, s2 = p2;
        #pragma unroll 8
        for (int i = 0; i < 64; ++i) {
            float mv = __shfl(mem, i);
            s1 += mv * Wm1[i][j];
            s2 += mv * Wm2[i][j];
        }
        float h1 = fmaxf(s1, 0.f);
        float h2 = fmaxf(s2, 0.f);
        // gamma = sigmoid(hid @ Wf + b2)
        float t1 = bf1, t2 = bf2;
        #pragma unroll 8
        for (int i = 0; i < 64; ++i) {
            t1 += __shfl(h1, i) * Wf1[i][j];
            t2 += __shfl(h2, i) * Wf2[i][j];
        }
        float g1 = 1.f / (1.f + expf(-t1));
        float g2 = 1.f / (1.f + expf(-t2));
        mem = g1 * mem + g2 * cj;
        cj = ncj; p1 = np1; p2 = np2;
    }

    // out[b] = relu([h_l h_a h_v mem] @ ow1) @ ow2
    float s = hp[((size_t)0 * BB + b) * 64 + j]
            + hp[((size_t)1 * BB + b) * 64 + j]
            + hp[((size_t)2 * BB + b) * 64 + j];
    #pragma unroll 8
    for (int i = 0; i < 64; ++i)
        s += __shfl(mem, i) * ow1[(192 + i) * 64 + j];
    float y = fmaxf(s, 0.f) * ow2[j];
    #pragma unroll
    for (int o = 32; o > 0; o >>= 1) y += __shfl_xor(y, o);
    if (j == 0) out[b] = y;
}

// ---------------------------------------------------------------------------
extern "C" void kernel_launch(void* const* d_in, const int* in_sizes, int n_in,
                              void* d_out, int out_size, void* d_ws, size_t ws_size,
                              hipStream_t stream)
{
    const float* x    = (const float*)d_in[0];
    const float* wihl = (const float*)d_in[1];
    const float* whhl = (const float*)d_in[2];
    const float* wiha = (const float*)d_in[3];
    const float* whha = (const float*)d_in[4];
    const float* wihv = (const float*)d_in[5];
    const float* whhv = (const float*)d_in[6];
    const float* a1w1 = (const float*)d_in[7];
    const float* a1b1 = (const float*)d_in[8];
    const float* a1w2 = (const float*)d_in[9];
    const float* a1b2 = (const float*)d_in[10];
    const float* a2w1 = (const float*)d_in[11];
    const float* a2b1 = (const float*)d_in[12];
    const float* a2w2 = (const float*)d_in[13];
    const float* a2b2 = (const float*)d_in[14];
    const float* g1w1 = (const float*)d_in[15];
    const float* g1b1 = (const float*)d_in[16];
    const float* g1w2 = (const float*)d_in[17];
    const float* g1b2 = (const float*)d_in[18];
    const float* g2w1 = (const float*)d_in[19];
    const float* g2b1 = (const float*)d_in[20];
    const float* g2w2 = (const float*)d_in[21];
    const float* g2b2 = (const float*)d_in[22];
    const float* ow1  = (const float*)d_in[23];
    const float* ow2  = (const float*)d_in[24];

    float* gx  = (float*)d_ws;             // 51200*768 floats = 157.3 MB
    float* hp  = (float*)d_ws + HPOFF;     // 3*256*64 floats  = 196 KB
    float* out = (float*)d_out;

    proj_kernel<<<dim3(800, 3, 1), dim3(256, 1, 1), 0, stream>>>(
        x, wihl, wiha, wihv, gx);

    lstm_kernel<<<dim3(3, 32, 1), dim3(256, 1, 1), 0, stream>>>(
        gx, whhl, whha, whhv, ow1, hp);

    att_kernel<<<dim3(1600, 1, 1), dim3(256, 1, 1), 0, stream>>>(
        gx,
        a1w1, a1b1, a1w2, a1b2,
        a2w1, a2b1, a2w2, a2b2,
        g1w1, g1b1, g2w1, g2b1);

    mem_kernel<<<dim3(256, 1, 1), dim3(64, 1, 1), 0, stream>>>(
        gx, g1w1, g1w2, g1b2, g2w1, g2w2, g2b2, ow1, ow2, hp, out);
}